// Round 7
// baseline (887.615 us; speedup 1.0000x reference)
//
#include <hip/hip_runtime.h>
#include <math.h>
#include <stdint.h>
#include <stddef.h>

#define BLOCK  256
#define S4     4
#define F32    32
#define E16    16
#define E16P   20               // padded LDS row (spreads perm-gathered reads)
#define LTOT   32
#define LSPLIT 8
#define LPB    (LTOT / LSPLIT)  // 4 kernels per block
#define EPSF   1e-8f
#define HPI    1.57079632679489662f

__device__ __forceinline__ float dot4(const float4 a, const float4 b) {
    return a.x*b.x + a.y*b.y + a.z*b.z + a.w*b.w;
}
__device__ __forceinline__ float sqd4(const float4 a, const float4 b) {
    float x = a.x-b.x, y = a.y-b.y, z = a.z-b.z, w = a.w-b.w;
    return x*x + y*y + z*z + w*w;
}
// d >= 0; d == 0 -> 1/0 = +inf -> atanf(inf) = pi/2 (matches jnp.arctan)
__device__ __forceinline__ float atan_inv(float d) {
    return atanf(1.0f / d);
}

// R2: (256,4) -> 64 VGPR + 2.4GB spill.  R3: cross-l acc (64 live) -> 128 VGPR
// + 1.2GB spill.  R5: sequential-l re-streaming -> spill-free (WRITE 6.4MB ✓)
// but 224 float4 VMEM/thread -> 1.02GB L2-miss, latency-bound at 298us.
// R6: two passes, phase-local residency: pass1 xn in regs (32) + acc(16);
// pass2 slot-streamed edge + center. Peak live ~95 regs, ~63 VMEM/thread.
__global__ __launch_bounds__(BLOCK, 2)
void kconv_kernel(const float* __restrict__ x_focal,
                  const float* __restrict__ p_focal,
                  const float* __restrict__ x_neighbor,
                  const float* __restrict__ p_neighbor,
                  const float* __restrict__ edge_attr_neighbor,
                  const float* __restrict__ x_center,
                  const float* __restrict__ x_support,
                  const float* __restrict__ edge_attr_support,
                  const float* __restrict__ p_support,
                  float* __restrict__ out, int N)
{
    // ---- L-side tables for THIS block's LPB kernels only (~4 KB LDS) ----
    __shared__ float s_xsup [LPB*S4*F32];   // 2 KB
    __shared__ float s_esup [LPB*S4*E16P];  // 1.25 KB (padded rows)
    __shared__ float s_xc   [LPB*F32];      // 0.5 KB
    __shared__ float s_sqsup[LPB];
    __shared__ float s_ncos [LPB*16];       // pairwise cos table
    __shared__ float s_nrm  [LPB*S4];

    const int tid = threadIdx.x;
    const int l0  = blockIdx.y * LPB;

    for (int i = tid; i < LPB*S4*F32/4; i += BLOCK)
        ((float4*)s_xsup)[i] = ((const float4*)(x_support + l0*S4*F32))[i];
    for (int i = tid; i < LPB*S4*(E16/4); i += BLOCK) {
        const int row = i / (E16/4), c = i % (E16/4);
        ((float4*)(s_esup + row*E16P))[c] =
            ((const float4*)(edge_attr_support + (l0*S4 + row)*E16))[c];
    }
    for (int i = tid; i < LPB*F32/4; i += BLOCK)
        ((float4*)s_xc)[i] = ((const float4*)(x_center + l0*F32))[i];

    if (tid < LPB) {
        const int l = l0 + tid;
        float s = 0.f;
        const float4* xs = (const float4*)(x_support + l*(S4*F32));
        #pragma unroll
        for (int c = 0; c < S4*F32/4; ++c) { float4 v = xs[c]; s += dot4(v, v); }
        s_sqsup[tid] = s;

        float ps[S4][3];
        #pragma unroll
        for (int q = 0; q < S4; ++q)
            #pragma unroll
            for (int k = 0; k < 3; ++k)
                ps[q][k] = p_support[(l*S4 + q)*3 + k];
        float nr[S4], nc[S4];
        #pragma unroll
        for (int q = 0; q < S4; ++q) {
            nr[q] = sqrtf(ps[q][0]*ps[q][0] + ps[q][1]*ps[q][1] + ps[q][2]*ps[q][2]);
            s_nrm[tid*S4 + q] = nr[q];
            nc[q] = fmaxf(nr[q], EPSF);
        }
        #pragma unroll
        for (int a = 0; a < S4; ++a)
            #pragma unroll
            for (int b = 0; b < S4; ++b) {
                float d = ps[a][0]*ps[b][0] + ps[a][1]*ps[b][1] + ps[a][2]*ps[b][2];
                s_ncos[tid*16 + a*4 + b] = d / (nc[a]*nc[b]);
            }
    }
    __syncthreads();

    const int n = blockIdx.x * BLOCK + tid;
    if (n >= N) return;                     // no barriers after this point

    // ---- geometry (persistent: len_nei, inn) ----
    float len_nei[S4], inn[S4];
    {
        float pf[3], pnv[S4][3];
        #pragma unroll
        for (int k = 0; k < 3; ++k) pf[k] = p_focal[n*3 + k];
        #pragma unroll
        for (int s = 0; s < S4; ++s)
            #pragma unroll
            for (int k = 0; k < 3; ++k)
                pnv[s][k] = p_neighbor[((size_t)n*S4 + s)*3 + k] - pf[k];
        #pragma unroll
        for (int s = 0; s < S4; ++s)
            len_nei[s] = sqrtf(pnv[s][0]*pnv[s][0] + pnv[s][1]*pnv[s][1] + pnv[s][2]*pnv[s][2]);
        #pragma unroll
        for (int s = 0; s < S4; ++s) {
            const int a = (s + 3) & 3;      // roll(+1): q[s] = p[s-1]
            float d = pnv[a][0]*pnv[s][0] + pnv[a][1]*pnv[s][1] + pnv[a][2]*pnv[s][2];
            inn[s] = d / (fmaxf(len_nei[a], EPSF) * fmaxf(len_nei[s], EPSF));
        }
    }

    // lexicographic permutations of (0,1,2,3) (itertools.permutations order)
    constexpr int PERM[24][4] = {
        {0,1,2,3},{0,1,3,2},{0,2,1,3},{0,2,3,1},{0,3,1,2},{0,3,2,1},
        {1,0,2,3},{1,0,3,2},{1,2,0,3},{1,2,3,0},{1,3,0,2},{1,3,2,0},
        {2,0,1,3},{2,0,3,1},{2,1,0,3},{2,1,3,0},{2,3,0,1},{2,3,1,0},
        {3,0,1,2},{3,0,2,1},{3,1,0,2},{3,1,2,0},{3,2,0,1},{3,2,1,0}
    };

    float    pt [LPB];
    uint32_t pks[LPB];

    // ============ Pass 1: xn resident in regs; per-li dots + 3 scores ============
    {
        float4 xn[S4*F32/4];                // 32 VGPRs, dies at end of pass 1
        const float4* xng = (const float4*)(x_neighbor + (size_t)n*(S4*F32));
        #pragma unroll
        for (int i = 0; i < S4*F32/4; ++i) xn[i] = xng[i];

        float sq_nei = 0.f;
        #pragma unroll
        for (int i = 0; i < S4*F32/4; ++i) sq_nei += dot4(xn[i], xn[i]);

        #pragma unroll 1
        for (int li = 0; li < LPB; ++li) {
            float acc[S4][S4];
            #pragma unroll
            for (int s = 0; s < S4; ++s)
                #pragma unroll
                for (int t = 0; t < S4; ++t) acc[s][t] = 0.f;

            const float4* supb = (const float4*)(s_xsup + li*(S4*F32));
            #pragma unroll
            for (int c = 0; c < F32/4; ++c) {
                #pragma unroll
                for (int t = 0; t < S4; ++t) {
                    float4 sv = supb[t*(F32/4) + c];   // wave-uniform LDS: broadcast
                    acc[0][t] += dot4(xn[0*(F32/4) + c], sv);
                    acc[1][t] += dot4(xn[1*(F32/4) + c], sv);
                    acc[2][t] += dot4(xn[2*(F32/4) + c], sv);
                    acc[3][t] += dot4(xn[3*(F32/4) + c], sv);
                }
            }

            // fold 24 perms: argmin d, first occurrence
            const float base = sq_nei + s_sqsup[li];
            float best_d = 3.4e38f;
            uint32_t best_pk = 0u;
            #pragma unroll
            for (int p = 0; p < 24; ++p) {
                float cross = acc[0][PERM[p][0]] + acc[1][PERM[p][1]]
                            + acc[2][PERM[p][2]] + acc[3][PERM[p][3]];
                float d = fmaxf(base - 2.0f*cross, 0.0f);
                uint32_t pk = (uint32_t)PERM[p][0] | ((uint32_t)PERM[p][1] << 8)
                            | ((uint32_t)PERM[p][2] << 16) | ((uint32_t)PERM[p][3] << 24);
                if (d < best_d) { best_d = d; best_pk = pk; }
            }
            const float sup_sc = atan_inv(best_d);

            const int pm0 = (int)( best_pk        & 3u);
            const int pm1 = (int)((best_pk >> 8)  & 3u);
            const int pm2 = (int)((best_pk >> 16) & 3u);
            const int pm3 = (int)((best_pk >> 24) & 3u);

            const float* ncs = s_ncos + li*16;
            float a0 = inn[0] - ncs[pm3*4 + pm0];   // a = (s+3)&3
            float a1 = inn[1] - ncs[pm0*4 + pm1];
            float a2 = inn[2] - ncs[pm1*4 + pm2];
            float a3 = inn[3] - ncs[pm2*4 + pm3];
            const float ang_sc = atan_inv(a0*a0 + a1*a1 + a2*a2 + a3*a3);

            const float* nr = s_nrm + li*S4;
            float b0 = len_nei[0] - nr[pm0];
            float b1 = len_nei[1] - nr[pm1];
            float b2 = len_nei[2] - nr[pm2];
            float b3 = len_nei[3] - nr[pm3];
            const float len_sc = atan_inv(b0*b0 + b1*b1 + b2*b2 + b3*b3);

            float t0 = len_sc - HPI, t1 = ang_sc - HPI, t2 = sup_sc - HPI;
            pt [li] = t0*t0 + t1*t1 + t2*t2;
            pks[li] = best_pk;
        }
    }   // xn dead

    // ============ Pass 2a: edge score, slot-streamed (ev loaded once) ============
    {
        float ed[LPB];
        #pragma unroll
        for (int li = 0; li < LPB; ++li) ed[li] = 0.f;
        const float4* evg = (const float4*)(edge_attr_neighbor + (size_t)n*(S4*E16));
        #pragma unroll
        for (int s = 0; s < S4; ++s) {
            float4 e0 = evg[s*(E16/4) + 0];
            float4 e1 = evg[s*(E16/4) + 1];
            float4 e2 = evg[s*(E16/4) + 2];
            float4 e3 = evg[s*(E16/4) + 3];
            #pragma unroll
            for (int li = 0; li < LPB; ++li) {
                const int pm_s = (int)((pks[li] >> (8*s)) & 3u);
                const float4* er = (const float4*)(s_esup + (li*S4 + pm_s)*E16P);
                ed[li] += sqd4(e0, er[0]) + sqd4(e1, er[1])
                        + sqd4(e2, er[2]) + sqd4(e3, er[3]);
            }
        }
        #pragma unroll
        for (int li = 0; li < LPB; ++li) {
            float te = atan_inv(ed[li]) - HPI;
            pt[li] += te*te;
        }
    }

    // ============ Pass 2b: center score (xf streamed once) + final ============
    {
        float cd[LPB];
        #pragma unroll
        for (int li = 0; li < LPB; ++li) cd[li] = 0.f;
        const float4* xfg = (const float4*)(x_focal + (size_t)n*F32);
        const float4* xc4 = (const float4*)s_xc;
        #pragma unroll
        for (int c = 0; c < F32/4; ++c) {
            float4 xf = xfg[c];
            #pragma unroll
            for (int li = 0; li < LPB; ++li)
                cd[li] += sqd4(xf, xc4[li*(F32/4) + c]);
        }
        #pragma unroll
        for (int li = 0; li < LPB; ++li) {
            float tc = atan_inv(cd[li]) - HPI;
            float total = pt[li] + tc*tc;
            out[(size_t)(l0 + li)*N + n] = atan_inv(total);
        }
    }
}

extern "C" void kernel_launch(void* const* d_in, const int* in_sizes, int n_in,
                              void* d_out, int out_size, void* d_ws, size_t ws_size,
                              hipStream_t stream) {
    const float* x_focal            = (const float*)d_in[0];
    const float* p_focal            = (const float*)d_in[1];
    const float* x_neighbor         = (const float*)d_in[2];
    const float* p_neighbor         = (const float*)d_in[3];
    const float* edge_attr_neighbor = (const float*)d_in[4];
    const float* x_center           = (const float*)d_in[5];
    const float* x_support          = (const float*)d_in[6];
    const float* edge_attr_support  = (const float*)d_in[7];
    const float* p_support          = (const float*)d_in[8];
    float* outp = (float*)d_out;

    const int N = in_sizes[0] / F32;        // x_focal is [N, 32]
    dim3 grid((N + BLOCK - 1) / BLOCK, LSPLIT);
    hipLaunchKernelGGL(kconv_kernel, grid, dim3(BLOCK), 0, stream,
                       x_focal, p_focal, x_neighbor, p_neighbor, edge_attr_neighbor,
                       x_center, x_support, edge_attr_support, p_support, outp, N);
}

// Round 10
// 394.198 us; speedup vs baseline: 2.2517x; 2.2517x over previous
//
#include <hip/hip_runtime.h>
#include <math.h>
#include <stdint.h>
#include <stddef.h>

#define BLOCK  256
#define S4     4
#define F32    32
#define E16    16
#define E16P   20               // padded LDS row (spreads perm-gathered reads)
#define LTOT   32
#define LSPLIT 8
#define LPB    (LTOT / LSPLIT)  // 4 kernels per block
#define EPSF   1e-8f
#define HPI    1.57079632679489662f

__device__ __forceinline__ float dot4(const float4 a, const float4 b) {
    return a.x*b.x + a.y*b.y + a.z*b.z + a.w*b.w;
}
__device__ __forceinline__ float sqd4(const float4 a, const float4 b) {
    float x = a.x-b.x, y = a.y-b.y, z = a.z-b.z, w = a.w-b.w;
    return x*x + y*y + z*z + w*w;
}
// d >= 0; d == 0 -> 1/0 = +inf -> atanf(inf) = pi/2 (matches jnp.arctan)
__device__ __forceinline__ float atan_inv(float d) {
    return atanf(1.0f / d);
}

// Hard-won law (R2/R3/R7): any phase with live floats > ~100 spills; the
// allocator NEVER allocates above the 128-VGPR tier (prefers scratch).
// R7 bug: xn[32] of float4 = 128 VGPRs (not 32!) -> 590MB spill, 785us.
// R5 (spill-free, per-li re-stream) = 298us @ 1.02GB FETCH.
// R8: pair-processing. Per pair: acc[2][4][4]=32 live + 16 transient.
// xn read 2x/y-block (was 4x), ev/xf once. ~93 float4/thread (was 229).
__global__ __launch_bounds__(BLOCK, 2)
void kconv_kernel(const float* __restrict__ x_focal,
                  const float* __restrict__ p_focal,
                  const float* __restrict__ x_neighbor,
                  const float* __restrict__ p_neighbor,
                  const float* __restrict__ edge_attr_neighbor,
                  const float* __restrict__ x_center,
                  const float* __restrict__ x_support,
                  const float* __restrict__ edge_attr_support,
                  const float* __restrict__ p_support,
                  float* __restrict__ out, int N)
{
    // ---- L-side tables for THIS block's LPB kernels only (~4 KB LDS) ----
    __shared__ float s_xsup [LPB*S4*F32];   // 2 KB
    __shared__ float s_esup [LPB*S4*E16P];  // 1.25 KB (padded rows)
    __shared__ float s_xc   [LPB*F32];      // 0.5 KB
    __shared__ float s_sqsup[LPB];
    __shared__ float s_ncos [LPB*16];       // pairwise cos table
    __shared__ float s_nrm  [LPB*S4];

    const int tid = threadIdx.x;
    const int l0  = blockIdx.y * LPB;

    for (int i = tid; i < LPB*S4*F32/4; i += BLOCK)
        ((float4*)s_xsup)[i] = ((const float4*)(x_support + l0*S4*F32))[i];
    for (int i = tid; i < LPB*S4*(E16/4); i += BLOCK) {
        const int row = i / (E16/4), c = i % (E16/4);
        ((float4*)(s_esup + row*E16P))[c] =
            ((const float4*)(edge_attr_support + (l0*S4 + row)*E16))[c];
    }
    for (int i = tid; i < LPB*F32/4; i += BLOCK)
        ((float4*)s_xc)[i] = ((const float4*)(x_center + l0*F32))[i];

    if (tid < LPB) {
        const int l = l0 + tid;
        float s = 0.f;
        const float4* xs = (const float4*)(x_support + l*(S4*F32));
        #pragma unroll
        for (int c = 0; c < S4*F32/4; ++c) { float4 v = xs[c]; s += dot4(v, v); }
        s_sqsup[tid] = s;

        float ps[S4][3];
        #pragma unroll
        for (int q = 0; q < S4; ++q)
            #pragma unroll
            for (int k = 0; k < 3; ++k)
                ps[q][k] = p_support[(l*S4 + q)*3 + k];
        float nr[S4], nc[S4];
        #pragma unroll
        for (int q = 0; q < S4; ++q) {
            nr[q] = sqrtf(ps[q][0]*ps[q][0] + ps[q][1]*ps[q][1] + ps[q][2]*ps[q][2]);
            s_nrm[tid*S4 + q] = nr[q];
            nc[q] = fmaxf(nr[q], EPSF);
        }
        #pragma unroll
        for (int a = 0; a < S4; ++a)
            #pragma unroll
            for (int b = 0; b < S4; ++b) {
                float d = ps[a][0]*ps[b][0] + ps[a][1]*ps[b][1] + ps[a][2]*ps[b][2];
                s_ncos[tid*16 + a*4 + b] = d / (nc[a]*nc[b]);
            }
    }
    __syncthreads();

    const int n = blockIdx.x * BLOCK + tid;
    if (n >= N) return;                     // no barriers after this point

    // ---- geometry (persistent: len_nei, inn ~ 8 regs) ----
    float len_nei[S4], inn[S4];
    {
        float pf[3], pnv[S4][3];
        #pragma unroll
        for (int k = 0; k < 3; ++k) pf[k] = p_focal[n*3 + k];
        #pragma unroll
        for (int s = 0; s < S4; ++s)
            #pragma unroll
            for (int k = 0; k < 3; ++k)
                pnv[s][k] = p_neighbor[((size_t)n*S4 + s)*3 + k] - pf[k];
        #pragma unroll
        for (int s = 0; s < S4; ++s)
            len_nei[s] = sqrtf(pnv[s][0]*pnv[s][0] + pnv[s][1]*pnv[s][1] + pnv[s][2]*pnv[s][2]);
        #pragma unroll
        for (int s = 0; s < S4; ++s) {
            const int a = (s + 3) & 3;      // roll(+1): q[s] = p[s-1]
            float d = pnv[a][0]*pnv[s][0] + pnv[a][1]*pnv[s][1] + pnv[a][2]*pnv[s][2];
            inn[s] = d / (fmaxf(len_nei[a], EPSF) * fmaxf(len_nei[s], EPSF));
        }
    }

    // lexicographic permutations of (0,1,2,3) (itertools.permutations order)
    constexpr int PERM[24][4] = {
        {0,1,2,3},{0,1,3,2},{0,2,1,3},{0,2,3,1},{0,3,1,2},{0,3,2,1},
        {1,0,2,3},{1,0,3,2},{1,2,0,3},{1,2,3,0},{1,3,0,2},{1,3,2,0},
        {2,0,1,3},{2,0,3,1},{2,1,0,3},{2,1,3,0},{2,3,0,1},{2,3,1,0},
        {3,0,1,2},{3,0,2,1},{3,1,0,2},{3,1,2,0},{3,2,0,1},{3,2,1,0}
    };

    const float4* xng = (const float4*)(x_neighbor + (size_t)n*(S4*F32));

    float sq_nei = 0.f;
    float pt0, pt1, pt2, pt3;
    uint32_t pk0, pk1, pk2, pk3;

    // fold one l's 4x4 dot matrix into (pt, pk)
    auto fold_one = [&](const float (&a)[S4][S4], const int li,
                        float& ptO, uint32_t& pkO) {
        const float base = sq_nei + s_sqsup[li];
        float best_d = 3.4e38f;
        uint32_t best_pk = 0u;
        #pragma unroll
        for (int p = 0; p < 24; ++p) {
            float cross = a[0][PERM[p][0]] + a[1][PERM[p][1]]
                        + a[2][PERM[p][2]] + a[3][PERM[p][3]];
            float d = fmaxf(base - 2.0f*cross, 0.0f);
            uint32_t pk = (uint32_t)PERM[p][0] | ((uint32_t)PERM[p][1] << 8)
                        | ((uint32_t)PERM[p][2] << 16) | ((uint32_t)PERM[p][3] << 24);
            if (d < best_d) { best_d = d; best_pk = pk; }   // first occurrence
        }
        const float sup_sc = atan_inv(best_d);

        const int pm0 = (int)( best_pk        & 3u);
        const int pm1 = (int)((best_pk >> 8)  & 3u);
        const int pm2 = (int)((best_pk >> 16) & 3u);
        const int pm3 = (int)((best_pk >> 24) & 3u);

        const float* ncs = s_ncos + li*16;
        float a0 = inn[0] - ncs[pm3*4 + pm0];   // a = (s+3)&3
        float a1 = inn[1] - ncs[pm0*4 + pm1];
        float a2 = inn[2] - ncs[pm1*4 + pm2];
        float a3 = inn[3] - ncs[pm2*4 + pm3];
        const float ang_sc = atan_inv(a0*a0 + a1*a1 + a2*a2 + a3*a3);

        const float* nr = s_nrm + li*S4;
        float b0 = len_nei[0] - nr[pm0];
        float b1 = len_nei[1] - nr[pm1];
        float b2 = len_nei[2] - nr[pm2];
        float b3 = len_nei[3] - nr[pm3];
        const float len_sc = atan_inv(b0*b0 + b1*b1 + b2*b2 + b3*b3);

        float t0 = len_sc - HPI, t1 = ang_sc - HPI, t2 = sup_sc - HPI;
        ptO = t0*t0 + t1*t1 + t2*t2;
        pkO = best_pk;
    };

    // dot phase for a PAIR of l's: acc[2][4][4]=32 live, 16 transient loads
    auto do_pair = [&](const int liA, const int liB, const bool first,
                       float& ptA, float& ptB, uint32_t& pkA, uint32_t& pkB) {
        float acc[2][S4][S4];
        #pragma unroll
        for (int g = 0; g < 2; ++g)
            #pragma unroll
            for (int s = 0; s < S4; ++s)
                #pragma unroll
                for (int t = 0; t < S4; ++t) acc[g][s][t] = 0.f;

        const float4* supA = (const float4*)(s_xsup + liA*(S4*F32));
        const float4* supB = (const float4*)(s_xsup + liB*(S4*F32));
        #pragma unroll 4
        for (int c = 0; c < F32/4; ++c) {
            float4 xv0 = xng[0*(F32/4) + c];
            float4 xv1 = xng[1*(F32/4) + c];
            float4 xv2 = xng[2*(F32/4) + c];
            float4 xv3 = xng[3*(F32/4) + c];
            if (first)
                sq_nei += dot4(xv0,xv0) + dot4(xv1,xv1) + dot4(xv2,xv2) + dot4(xv3,xv3);
            #pragma unroll
            for (int t = 0; t < S4; ++t) {
                float4 svA = supA[t*(F32/4) + c];   // wave-uniform LDS: broadcast
                acc[0][0][t] += dot4(xv0, svA);
                acc[0][1][t] += dot4(xv1, svA);
                acc[0][2][t] += dot4(xv2, svA);
                acc[0][3][t] += dot4(xv3, svA);
                float4 svB = supB[t*(F32/4) + c];
                acc[1][0][t] += dot4(xv0, svB);
                acc[1][1][t] += dot4(xv1, svB);
                acc[1][2][t] += dot4(xv2, svB);
                acc[1][3][t] += dot4(xv3, svB);
            }
        }
        fold_one(acc[0], liA, ptA, pkA);
        fold_one(acc[1], liB, ptB, pkB);
    };

    do_pair(0, 1, true,  pt0, pt1, pk0, pk1);
    __builtin_amdgcn_sched_barrier(0);   // forbid merging the two pair-streams
    do_pair(2, 3, false, pt2, pt3, pk2, pk3);
    __builtin_amdgcn_sched_barrier(0);   // forbid hoisting edge loads into dots

    // ---- edge score: ev loaded once, slot-streamed (live ~40 regs) ----
    {
        float ed0 = 0.f, ed1 = 0.f, ed2 = 0.f, ed3 = 0.f;
        const float4* evg = (const float4*)(edge_attr_neighbor + (size_t)n*(S4*E16));
        #pragma unroll
        for (int s = 0; s < S4; ++s) {
            float4 e0 = evg[s*(E16/4) + 0];
            float4 e1 = evg[s*(E16/4) + 1];
            float4 e2 = evg[s*(E16/4) + 2];
            float4 e3 = evg[s*(E16/4) + 3];
#define EDGE_LI(idx, pk, ed)                                                   \
            {                                                                  \
                const int pm_s = (int)(((pk) >> (8*s)) & 3u);                  \
                const float4* er = (const float4*)(s_esup + ((idx)*S4 + pm_s)*E16P); \
                ed += sqd4(e0, er[0]) + sqd4(e1, er[1])                        \
                    + sqd4(e2, er[2]) + sqd4(e3, er[3]);                       \
            }
            EDGE_LI(0, pk0, ed0)
            EDGE_LI(1, pk1, ed1)
            EDGE_LI(2, pk2, ed2)
            EDGE_LI(3, pk3, ed3)
#undef EDGE_LI
        }
        float te0 = atan_inv(ed0) - HPI; pt0 += te0*te0;
        float te1 = atan_inv(ed1) - HPI; pt1 += te1*te1;
        float te2 = atan_inv(ed2) - HPI; pt2 += te2*te2;
        float te3 = atan_inv(ed3) - HPI; pt3 += te3*te3;
    }

    // ---- center score: xf loaded once, streamed vs 4 centers + final ----
    {
        float cd0 = 0.f, cd1 = 0.f, cd2 = 0.f, cd3 = 0.f;
        const float4* xfg = (const float4*)(x_focal + (size_t)n*F32);
        const float4* xc4 = (const float4*)s_xc;
        #pragma unroll 4
        for (int c = 0; c < F32/4; ++c) {
            float4 xf = xfg[c];
            cd0 += sqd4(xf, xc4[0*(F32/4) + c]);
            cd1 += sqd4(xf, xc4[1*(F32/4) + c]);
            cd2 += sqd4(xf, xc4[2*(F32/4) + c]);
            cd3 += sqd4(xf, xc4[3*(F32/4) + c]);
        }
        float tc0 = atan_inv(cd0) - HPI;
        float tc1 = atan_inv(cd1) - HPI;
        float tc2 = atan_inv(cd2) - HPI;
        float tc3 = atan_inv(cd3) - HPI;
        out[(size_t)(l0 + 0)*N + n] = atan_inv(pt0 + tc0*tc0);
        out[(size_t)(l0 + 1)*N + n] = atan_inv(pt1 + tc1*tc1);
        out[(size_t)(l0 + 2)*N + n] = atan_inv(pt2 + tc2*tc2);
        out[(size_t)(l0 + 3)*N + n] = atan_inv(pt3 + tc3*tc3);
    }
}

extern "C" void kernel_launch(void* const* d_in, const int* in_sizes, int n_in,
                              void* d_out, int out_size, void* d_ws, size_t ws_size,
                              hipStream_t stream) {
    const float* x_focal            = (const float*)d_in[0];
    const float* p_focal            = (const float*)d_in[1];
    const float* x_neighbor         = (const float*)d_in[2];
    const float* p_neighbor         = (const float*)d_in[3];
    const float* edge_attr_neighbor = (const float*)d_in[4];
    const float* x_center           = (const float*)d_in[5];
    const float* x_support          = (const float*)d_in[6];
    const float* edge_attr_support  = (const float*)d_in[7];
    const float* p_support          = (const float*)d_in[8];
    float* outp = (float*)d_out;

    const int N = in_sizes[0] / F32;        // x_focal is [N, 32]
    dim3 grid((N + BLOCK - 1) / BLOCK, LSPLIT);
    hipLaunchKernelGGL(kconv_kernel, grid, dim3(BLOCK), 0, stream,
                       x_focal, p_focal, x_neighbor, p_neighbor, edge_attr_neighbor,
                       x_center, x_support, edge_attr_support, p_support, outp, N);
}